// Round 6
// baseline (124.477 us; speedup 1.0000x reference)
//
#include <hip/hip_runtime.h>
#include <math.h>

#define Nn 100000
#define Ee 1600000
#define IND 128
#define OUTD 64
#define DPB 64                      // dsts per bucket (dst>>6)
#define NB 1563                     // ceil(Nn/DPB)
#define BSTR 1536                   // fixed bins slots per bucket (== CAP)
#define CAP 1536                    // LDS record capacity in k_agg
#define GB 1563                     // gemm blocks (64 rows each)
#define EB_BLOCKS 391               // edge chunk blocks (4096 edges each)
#define AGG_BLOCKS 1024             // persistent k_agg blocks (4 per CU)
#define AFIX 1048576.0f             // alpha fixed-point scale (2^20)

using bf16x8 = __attribute__((ext_vector_type(8))) short;
using f32x4 = __attribute__((ext_vector_type(4))) float;

// ---------------------------------------------------------------------------
__device__ __forceinline__ unsigned short f2bf(float f) {
    unsigned u = __float_as_uint(f);
    u = u + 0x7FFFu + ((u >> 16) & 1u);   // round-to-nearest-even
    return (unsigned short)(u >> 16);
}
__device__ __forceinline__ float bf2f(unsigned short h) {
    return __uint_as_float(((unsigned)h) << 16);
}

// Self-detect int64 vs int32 edge_index: int32 data read as int64 has huge
// hi-words (P(all 8 in range) ~ 1e-40). Wave-uniform result.
__device__ __forceinline__ bool probe64(const void* __restrict__ ei) {
    const long long* p = (const long long*)ei;
    bool ok = true;
#pragma unroll
    for (int i = 0; i < 8; ++i) {
        long long v = p[i];
        ok = ok && (v >= 0 && v < Nn);
    }
    return ok;
}

__device__ __forceinline__ void load_edge(const void* ei, int e, bool is64,
                                          int& s, int& d) {
    if (is64) {
        const long long* p = (const long long*)ei;
        s = (int)p[e];
        d = (int)p[Ee + e];
    } else {
        const int* p = (const int*)ei;
        s = p[e];
        d = p[Ee + e];
    }
}

// ---------------------------------------------------------------------------
// R22: GEMM only (histogram role deleted — bins are fixed-stride now, no
// scan needed). Whb(bf16) = h @ W^T; s1 = Wh.a[:64]; s2 = Wh.a[64:].
__global__ __launch_bounds__(256) void k_fused(
    const float* __restrict__ h, const float* __restrict__ W,
    const float* __restrict__ a, unsigned short* __restrict__ Whb,
    float* __restrict__ s1, float* __restrict__ s2) {
    __shared__ unsigned short Ash[64][136];  // 17.4 KB (+8 u16 pad per row)
    __shared__ unsigned short Wsh[64][136];  // 17.4 KB
    __shared__ float al[2 * OUTD];
    int bid = blockIdx.x;
    int t = threadIdx.x;

    int R = bid * 64;
    // stage W (f32 -> bf16), coalesced
    for (int i = t; i < 2048; i += 256) {  // 64 rows x 32 float4
        float4 v = ((const float4*)W)[i];
        int r = i >> 5, c = (i & 31) << 2;
        unsigned lo = (unsigned)f2bf(v.x) | ((unsigned)f2bf(v.y) << 16);
        unsigned hi = (unsigned)f2bf(v.z) | ((unsigned)f2bf(v.w) << 16);
        *(uint2*)&Wsh[r][c] = make_uint2(lo, hi);
    }
    if (t < 32) ((float4*)al)[t] = ((const float4*)a)[t];
    // stage A tile (f32 -> bf16), coalesced, zero-pad tail rows
    for (int i = t; i < 2048; i += 256) {
        int r = i >> 5, c = (i & 31) << 2;
        int n = R + r;
        float4 v = make_float4(0.f, 0.f, 0.f, 0.f);
        if (n < Nn) v = ((const float4*)(h + (size_t)n * IND))[i & 31];
        unsigned lo = (unsigned)f2bf(v.x) | ((unsigned)f2bf(v.y) << 16);
        unsigned hi = (unsigned)f2bf(v.z) | ((unsigned)f2bf(v.w) << 16);
        *(uint2*)&Ash[r][c] = make_uint2(lo, hi);
    }
    __syncthreads();

    int w = t >> 6, l = t & 63;
    int li = l & 15, lg = l >> 4;
    f32x4 acc[4];
#pragma unroll
    for (int nt = 0; nt < 4; ++nt) acc[nt] = (f32x4){0.f, 0.f, 0.f, 0.f};
#pragma unroll
    for (int kk = 0; kk < 4; ++kk) {
        bf16x8 af = *(const bf16x8*)&Ash[w * 16 + li][kk * 32 + lg * 8];
#pragma unroll
        for (int nt = 0; nt < 4; ++nt) {
            bf16x8 bf = *(const bf16x8*)&Wsh[nt * 16 + li][kk * 32 + lg * 8];
            acc[nt] = __builtin_amdgcn_mfma_f32_16x16x32_bf16(af, bf,
                                                              acc[nt],
                                                              0, 0, 0);
        }
    }
    // store Whb (bf16) + build s1/s2 partials from f32 accs
    float p1[4] = {0.f, 0.f, 0.f, 0.f};
    float p2[4] = {0.f, 0.f, 0.f, 0.f};
#pragma unroll
    for (int nt = 0; nt < 4; ++nt) {
        float a1v = al[nt * 16 + li];
        float a2v = al[OUTD + nt * 16 + li];
#pragma unroll
        for (int r = 0; r < 4; ++r) {
            float v = acc[nt][r];
            p1[r] += v * a1v;
            p2[r] += v * a2v;
            int row = R + w * 16 + lg * 4 + r;
            if (row < Nn)
                Whb[(size_t)row * OUTD + nt * 16 + li] = f2bf(v);
        }
    }
    // reduce over the 16-lane col group (masks stay within group)
#pragma unroll
    for (int r = 0; r < 4; ++r) {
#pragma unroll
        for (int m = 1; m < 16; m <<= 1) {
            p1[r] += __shfl_xor(p1[r], m, 64);
            p2[r] += __shfl_xor(p2[r], m, 64);
        }
    }
    if (li < 4) {
        int row = R + w * 16 + lg * 4 + li;
        if (row < Nn) {
            s1[row] = p1[li];
            s2[row] = p2[li];
        }
    }
}

// ---------------------------------------------------------------------------
// R22 scatter into FIXED-STRIDE buckets (BSTR slots each; no histogram/scan):
//   bins[b*BSTR + rank] = ( (s<<7) | (dloc<<24) , alpha_fix_i20 )   [uint2]
// The .x word IS the Whb byte offset (s*128B rows) with dloc in bits 24-29.
// Block-local LDS ranks + ONE global cursor atomic per (block,bucket).
// P(Poisson(1024) > 1536) ~ 1e-57; writes clamped for safety.
// Alpha accumulation stays PER-BUCKET in LDS downstream (k_balpha) — R4's
// global atomicAdd(an+d) scatter was a 6x regression (1.6M random global
// atomics serialize at L2).
__global__ __launch_bounds__(512) void k_binscatter(
    const void* __restrict__ ei, const float* __restrict__ ew,
    const float* __restrict__ s1, const float* __restrict__ s2,
    int* __restrict__ bcursor, uint2* __restrict__ bins) {
    __shared__ int cnt[NB];
    __shared__ int gbase[NB];
    for (int i = threadIdx.x; i < NB; i += 512) cnt[i] = 0;
    __syncthreads();
    bool is64 = probe64(ei);
    int base = blockIdx.x * 4096;
    unsigned rx[8];
    int ryi[8];
    int rb[8];
    int rk[8];
#pragma unroll
    for (int i = 0; i < 8; ++i) {
        int e = base + i * 512 + threadIdx.x;
        rb[i] = -1;
        rx[i] = 0;
        ryi[i] = 0;
        rk[i] = 0;
        if (e < Ee) {
            int s, d;
            load_edge(ei, e, is64, s, d);
            float alpha = (s1[s] + s2[d]) * ew[e];
            ryi[i] = (int)rintf(alpha * AFIX);
            int b = d >> 6;
            rb[i] = b;
            rk[i] = atomicAdd(&cnt[b], 1);
            rx[i] = ((unsigned)s << 7) | ((unsigned)(d & 63) << 24);
        }
    }
    __syncthreads();
    for (int i = threadIdx.x; i < NB; i += 512) {
        int c = cnt[i];
        if (c) gbase[i] = atomicAdd(bcursor + i, c);
    }
    __syncthreads();
#pragma unroll
    for (int i = 0; i < 8; ++i) {
        if (rb[i] >= 0) {
            int pos = gbase[rb[i]] + rk[i];
            if (pos < BSTR)
                bins[(size_t)rb[i] * BSTR + pos] =
                    make_uint2(rx[i], (unsigned)ryi[i]);
        }
    }
}

// ---------------------------------------------------------------------------
// Per-bucket alpha_node accumulation in LDS via NATIVE int ds_add (fixed
// point), then ae[n] = expf(an) directly. NO global-max shift (R16 note:
// the softmax ratio is shift-invariant; an is in ±~6 at this input scale).
__global__ __launch_bounds__(256) void k_balpha(
    const uint2* __restrict__ bins, const int* __restrict__ bcnt,
    float* __restrict__ ae) {
    __shared__ int anl[DPB];
    int b = blockIdx.x;
    int t = threadIdx.x;
    if (t < DPB) anl[t] = 0;
    __syncthreads();
    int e0 = b * BSTR;
    int c = bcnt[b];
    int e1 = e0 + (c < BSTR ? c : BSTR);
    for (int k = e0 + t; k < e1; k += 256) {
        uint2 r = bins[k];
        atomicAdd(&anl[r.x >> 24], (int)r.y);
    }
    __syncthreads();
    if (t < DPB) {
        int n = b * DPB + t;
        if (n < Nn) ae[n] = expf((float)anl[t] * (1.f / AFIX));
    }
}

// ---------------------------------------------------------------------------
// R22 aggregation: PERSISTENT blocks (1024 = 4/CU, work-stolen bucket ids)
// + QUARTER-WAVE gather.
//   * R5 arithmetic: 70 cy/record, 52% VALU issue, occupancy 53% (6.1
//     blocks/CU of work over a 4-block residency cap -> ragged refill).
//     Persistent blocks remove the refill tail and self-balance.
//   * Quarter-wave: 16 lanes per record, each lane loads a uint2 (4 dims,
//     8B); one gather instruction covers 4 records (was 2), one ds_read
//     covers 4 -> per-record VALU ~18 -> ~11.
// Phase 1 (once per bucket): dloc-rank records via LDS int atomics + shfl
// scan; stage (whb_byte_off, ae[src]) into LDS. Phase 2: 8 waves x 8 dlocs;
// register accumulation (float4/lane); flush via shfl_xor(16,32); fused
// denom/div/ELU; float4 stores.
#define AGG_BODY(NR)                                                         \
    {                                                                        \
        uint2 rr[NR];                                                        \
        uint2 ww[NR];                                                        \
        _Pragma("unroll") for (int j = 0; j < NR; ++j)                       \
            rr[j] = lp[4 * j];                                               \
        _Pragma("unroll") for (int j = 0; j < NR; ++j)                       \
            ww[j] = *(const uint2*)(whbB + (rr[j].x + ql8));                 \
        _Pragma("unroll") for (int j = 0; j < NR; ++j) {                     \
            float aa = __uint_as_float(rr[j].y);                             \
            acc.x += aa * __uint_as_float(ww[j].x << 16);                    \
            acc.y += aa * __uint_as_float(ww[j].x & 0xFFFF0000u);            \
            acc.z += aa * __uint_as_float(ww[j].y << 16);                    \
            acc.w += aa * __uint_as_float(ww[j].y & 0xFFFF0000u);            \
            den += aa;                                                       \
        }                                                                    \
        lp += 4 * NR;                                                        \
    }

__global__ __launch_bounds__(512, 4) void k_agg(
    const uint2* __restrict__ bins, const int* __restrict__ bcnt,
    const float* __restrict__ ae, const unsigned short* __restrict__ Whb,
    float* __restrict__ out, int* __restrict__ wctr) {
    __shared__ uint2 lrec[CAP];      // 12.3 KB (whb_byte_off, ae_f32)
    __shared__ int cnt[DPB];
    __shared__ int sbase[DPB];
    __shared__ int bsh;
    int t = threadIdx.x;
    int lane = t & 63;
    int wave = t >> 6;               // 0..7
    int q = lane >> 4;               // quarter: record k+q of each group of 4
    int ql = lane & 15;              // dim quad: dims 4*ql .. 4*ql+3
    unsigned ql8 = (unsigned)ql << 3;
    const char* whbB = (const char*)Whb;

    for (;;) {
        if (t == 0) bsh = atomicAdd(wctr, 1);
        if (t < DPB) cnt[t] = 0;
        __syncthreads();
        int b = bsh;
        if (b >= NB) break;
        int e0 = b * BSTR;
        int c = bcnt[b];
        int total = c < BSTR ? c : BSTR;
        int e1 = e0 + total;

        // ---- phase 1: stage + rank (once per bucket) ----
        unsigned su[CAP / 512];
        float sa[CAP / 512];
        int srk[CAP / 512];
#pragma unroll
        for (int i = 0; i < CAP / 512; ++i) {
            int k = e0 + i * 512 + t;
            srk[i] = -1;
            if (k < e1) {
                uint2 r = bins[k];
                srk[i] = atomicAdd(&cnt[r.x >> 24], 1);
                su[i] = r.x;
                sa[i] = ae[(r.x >> 7) & 0x1FFFF];
            }
        }
        __syncthreads();
        // single-wave inclusive shfl-scan of cnt -> sbase
        if (t < DPB) {
            int v = cnt[t];
#pragma unroll
            for (int d = 1; d < DPB; d <<= 1) {
                int u = __shfl_up(v, d, 64);
                if (t >= d) v += u;
            }
            sbase[t] = v;
        }
        __syncthreads();
        // scatter into dloc-sorted LDS order: (byte_off, ae bits)
#pragma unroll
        for (int i = 0; i < CAP / 512; ++i) {
            if (srk[i] >= 0) {
                int dloc = su[i] >> 24;
                int pos = sbase[dloc] - cnt[dloc] + srk[i];
                lrec[pos] = make_uint2(su[i] & 0x00FFFF80u,
                                       __float_as_uint(sa[i]));
            }
        }
        __syncthreads();

        // ---- phase 2: wave owns dlocs [wave*8, wave*8+8) ----
        for (int d = wave * 8; d < wave * 8 + 8; ++d) {
            int k1 = sbase[d];
            int k = k1 - cnt[d];
            const uint2* lp = lrec + k + q;
            float4 acc = make_float4(0.f, 0.f, 0.f, 0.f);
            float den = 0.f;
            for (; k + 15 < k1; k += 16) AGG_BODY(4);
            for (; k + 7 < k1; k += 8) AGG_BODY(2);
            for (; k + 3 < k1; k += 4) AGG_BODY(1);
            if (k < k1) {  // 1-3 record tail: clamp addr, zero alpha
                int idx = k + q;
                int cl = idx < k1 ? idx : k1 - 1;
                uint2 rA = lrec[cl];
                float aA = idx < k1 ? __uint_as_float(rA.y) : 0.f;
                uint2 wA = *(const uint2*)(whbB + (rA.x + ql8));
                acc.x += aA * __uint_as_float(wA.x << 16);
                acc.y += aA * __uint_as_float(wA.x & 0xFFFF0000u);
                acc.z += aA * __uint_as_float(wA.y << 16);
                acc.w += aA * __uint_as_float(wA.y & 0xFFFF0000u);
                den += aA;
            }
            // flush: combine quarters, divide, ELU, write float4
#pragma unroll
            for (int m = 16; m <= 32; m <<= 1) {
                acc.x += __shfl_xor(acc.x, m, 64);
                acc.y += __shfl_xor(acc.y, m, 64);
                acc.z += __shfl_xor(acc.z, m, 64);
                acc.w += __shfl_xor(acc.w, m, 64);
                den += __shfl_xor(den, m, 64);
            }
            if (q == 0) {
                int n = b * DPB + d;
                if (n < Nn) {
                    float inv = 1.f / (den + 1e-9f);
                    float vx = acc.x * inv;
                    float vy = acc.y * inv;
                    float vz = acc.z * inv;
                    float vw = acc.w * inv;
                    vx = vx > 0.f ? vx : expm1f(vx);
                    vy = vy > 0.f ? vy : expm1f(vy);
                    vz = vz > 0.f ? vz : expm1f(vz);
                    vw = vw > 0.f ? vw : expm1f(vw);
                    *(float4*)&out[(size_t)n * OUTD + ql * 4] =
                        make_float4(vx, vy, vz, vw);
                }
            }
        }
        __syncthreads();  // lrec/cnt/sbase reused next iteration
    }
}

// ---------------------------------------------------------------------------
extern "C" void kernel_launch(void* const* d_in, const int* in_sizes, int n_in,
                              void* d_out, int out_size, void* d_ws,
                              size_t ws_size, hipStream_t stream) {
    const float* h = (const float*)d_in[0];
    const void* ei = d_in[1];
    const float* ew = (const float*)d_in[2];
    const float* W = (const float*)d_in[3];
    const float* a = (const float*)d_in[4];
    float* out = (float*)d_out;

    unsigned short* Whb = (unsigned short*)d_ws;      // 6.4M u16 = 12.8 MB
    float* s1 = (float*)(Whb + (size_t)Nn * OUTD);    // 100,000 f
    float* s2 = s1 + Nn;                              // 100,000 f
    float* ae = s2 + Nn;                              // 100,000 f
    int* bcursor = (int*)(ae + Nn);                   // 2048 i [zeroed]
    int* wctr = bcursor + 2048;                       // 16 i   [zeroed]
    uint2* bins = (uint2*)(wctr + 16);                // NB*BSTR x 8B = 19.2MB

    hipMemsetAsync(bcursor, 0, (2048 + 16) * sizeof(int), stream);

    k_fused<<<GB, 256, 0, stream>>>(h, W, a, Whb, s1, s2);
    k_binscatter<<<EB_BLOCKS, 512, 0, stream>>>(ei, ew, s1, s2, bcursor, bins);
    k_balpha<<<NB, 256, 0, stream>>>(bins, bcursor, ae);
    k_agg<<<AGG_BLOCKS, 512, 0, stream>>>(bins, bcursor, ae, Whb, out, wctr);
}

// Round 7
// 107.634 us; speedup vs baseline: 1.1565x; 1.1565x over previous
//
#include <hip/hip_runtime.h>
#include <math.h>

#define Nn 100000
#define Ee 1600000
#define IND 128
#define OUTD 64
#define DPB 64                      // dsts per bucket (dst>>6)
#define NB 1563                     // ceil(Nn/DPB)
#define BSTR 1536                   // fixed bins slots per bucket (== CAP)
#define CAP 1536                    // LDS record capacity in k_agg
#define GB 1563                     // gemm blocks (64 rows each)
#define EB_BLOCKS 391               // edge chunk blocks (4096 edges each)
#define AFIX 1048576.0f             // alpha fixed-point scale (2^20)

using bf16x8 = __attribute__((ext_vector_type(8))) short;
using f32x4 = __attribute__((ext_vector_type(4))) float;

// ---------------------------------------------------------------------------
__device__ __forceinline__ unsigned short f2bf(float f) {
    unsigned u = __float_as_uint(f);
    u = u + 0x7FFFu + ((u >> 16) & 1u);   // round-to-nearest-even
    return (unsigned short)(u >> 16);
}
__device__ __forceinline__ float bf2f(unsigned short h) {
    return __uint_as_float(((unsigned)h) << 16);
}

// Self-detect int64 vs int32 edge_index: int32 data read as int64 has huge
// hi-words (P(all 8 in range) ~ 1e-40). Wave-uniform result.
__device__ __forceinline__ bool probe64(const void* __restrict__ ei) {
    const long long* p = (const long long*)ei;
    bool ok = true;
#pragma unroll
    for (int i = 0; i < 8; ++i) {
        long long v = p[i];
        ok = ok && (v >= 0 && v < Nn);
    }
    return ok;
}

__device__ __forceinline__ void load_edge(const void* ei, int e, bool is64,
                                          int& s, int& d) {
    if (is64) {
        const long long* p = (const long long*)ei;
        s = (int)p[e];
        d = (int)p[Ee + e];
    } else {
        const int* p = (const int*)ei;
        s = p[e];
        d = p[Ee + e];
    }
}

// ---------------------------------------------------------------------------
// GEMM only (R6: histogram role deleted — bins are fixed-stride, no scan).
// Whb(bf16) = h @ W^T; s1 = Wh.a[:64]; s2 = Wh.a[64:].
__global__ __launch_bounds__(256) void k_fused(
    const float* __restrict__ h, const float* __restrict__ W,
    const float* __restrict__ a, unsigned short* __restrict__ Whb,
    float* __restrict__ s1, float* __restrict__ s2) {
    __shared__ unsigned short Ash[64][136];  // 17.4 KB (+8 u16 pad per row)
    __shared__ unsigned short Wsh[64][136];  // 17.4 KB
    __shared__ float al[2 * OUTD];
    int bid = blockIdx.x;
    int t = threadIdx.x;

    int R = bid * 64;
    // stage W (f32 -> bf16), coalesced
    for (int i = t; i < 2048; i += 256) {  // 64 rows x 32 float4
        float4 v = ((const float4*)W)[i];
        int r = i >> 5, c = (i & 31) << 2;
        unsigned lo = (unsigned)f2bf(v.x) | ((unsigned)f2bf(v.y) << 16);
        unsigned hi = (unsigned)f2bf(v.z) | ((unsigned)f2bf(v.w) << 16);
        *(uint2*)&Wsh[r][c] = make_uint2(lo, hi);
    }
    if (t < 32) ((float4*)al)[t] = ((const float4*)a)[t];
    // stage A tile (f32 -> bf16), coalesced, zero-pad tail rows
    for (int i = t; i < 2048; i += 256) {
        int r = i >> 5, c = (i & 31) << 2;
        int n = R + r;
        float4 v = make_float4(0.f, 0.f, 0.f, 0.f);
        if (n < Nn) v = ((const float4*)(h + (size_t)n * IND))[i & 31];
        unsigned lo = (unsigned)f2bf(v.x) | ((unsigned)f2bf(v.y) << 16);
        unsigned hi = (unsigned)f2bf(v.z) | ((unsigned)f2bf(v.w) << 16);
        *(uint2*)&Ash[r][c] = make_uint2(lo, hi);
    }
    __syncthreads();

    int w = t >> 6, l = t & 63;
    int li = l & 15, lg = l >> 4;
    f32x4 acc[4];
#pragma unroll
    for (int nt = 0; nt < 4; ++nt) acc[nt] = (f32x4){0.f, 0.f, 0.f, 0.f};
#pragma unroll
    for (int kk = 0; kk < 4; ++kk) {
        bf16x8 af = *(const bf16x8*)&Ash[w * 16 + li][kk * 32 + lg * 8];
#pragma unroll
        for (int nt = 0; nt < 4; ++nt) {
            bf16x8 bf = *(const bf16x8*)&Wsh[nt * 16 + li][kk * 32 + lg * 8];
            acc[nt] = __builtin_amdgcn_mfma_f32_16x16x32_bf16(af, bf,
                                                              acc[nt],
                                                              0, 0, 0);
        }
    }
    // store Whb (bf16) + build s1/s2 partials from f32 accs
    float p1[4] = {0.f, 0.f, 0.f, 0.f};
    float p2[4] = {0.f, 0.f, 0.f, 0.f};
#pragma unroll
    for (int nt = 0; nt < 4; ++nt) {
        float a1v = al[nt * 16 + li];
        float a2v = al[OUTD + nt * 16 + li];
#pragma unroll
        for (int r = 0; r < 4; ++r) {
            float v = acc[nt][r];
            p1[r] += v * a1v;
            p2[r] += v * a2v;
            int row = R + w * 16 + lg * 4 + r;
            if (row < Nn)
                Whb[(size_t)row * OUTD + nt * 16 + li] = f2bf(v);
        }
    }
    // reduce over the 16-lane col group (masks stay within group)
#pragma unroll
    for (int r = 0; r < 4; ++r) {
#pragma unroll
        for (int m = 1; m < 16; m <<= 1) {
            p1[r] += __shfl_xor(p1[r], m, 64);
            p2[r] += __shfl_xor(p2[r], m, 64);
        }
    }
    if (li < 4) {
        int row = R + w * 16 + lg * 4 + li;
        if (row < Nn) {
            s1[row] = p1[li];
            s2[row] = p2[li];
        }
    }
}

// ---------------------------------------------------------------------------
// Scatter into FIXED-STRIDE buckets (BSTR slots each; no histogram/scan):
//   bins[b*BSTR + rank] = ( (s<<7) | (dloc<<24) , alpha_fix_i20 )   [uint2]
// The .x word IS the Whb byte offset (s*128B rows) with dloc in bits 24-29.
// Block-local LDS ranks + ONE global cursor atomic per (block,bucket).
// P(Poisson(1024) > 1536) ~ 1e-57; writes clamped for safety.
// Alpha accumulation stays PER-BUCKET in LDS downstream (k_balpha) — R4's
// global atomicAdd(an+d) scatter was a 6x regression (1.6M random global
// atomics serialize at L2).
__global__ __launch_bounds__(512) void k_binscatter(
    const void* __restrict__ ei, const float* __restrict__ ew,
    const float* __restrict__ s1, const float* __restrict__ s2,
    int* __restrict__ bcursor, uint2* __restrict__ bins) {
    __shared__ int cnt[NB];
    __shared__ int gbase[NB];
    for (int i = threadIdx.x; i < NB; i += 512) cnt[i] = 0;
    __syncthreads();
    bool is64 = probe64(ei);
    int base = blockIdx.x * 4096;
    unsigned rx[8];
    int ryi[8];
    int rb[8];
    int rk[8];
#pragma unroll
    for (int i = 0; i < 8; ++i) {
        int e = base + i * 512 + threadIdx.x;
        rb[i] = -1;
        rx[i] = 0;
        ryi[i] = 0;
        rk[i] = 0;
        if (e < Ee) {
            int s, d;
            load_edge(ei, e, is64, s, d);
            float alpha = (s1[s] + s2[d]) * ew[e];
            ryi[i] = (int)rintf(alpha * AFIX);
            int b = d >> 6;
            rb[i] = b;
            rk[i] = atomicAdd(&cnt[b], 1);
            rx[i] = ((unsigned)s << 7) | ((unsigned)(d & 63) << 24);
        }
    }
    __syncthreads();
    for (int i = threadIdx.x; i < NB; i += 512) {
        int c = cnt[i];
        if (c) gbase[i] = atomicAdd(bcursor + i, c);
    }
    __syncthreads();
#pragma unroll
    for (int i = 0; i < 8; ++i) {
        if (rb[i] >= 0) {
            int pos = gbase[rb[i]] + rk[i];
            if (pos < BSTR)
                bins[(size_t)rb[i] * BSTR + pos] =
                    make_uint2(rx[i], (unsigned)ryi[i]);
        }
    }
}

// ---------------------------------------------------------------------------
// Per-bucket alpha_node accumulation in LDS via NATIVE int ds_add (fixed
// point), then ae[n] = expf(an) directly. NO global-max shift (R16 note:
// the softmax ratio is shift-invariant; an is in ±~6 at this input scale).
__global__ __launch_bounds__(256) void k_balpha(
    const uint2* __restrict__ bins, const int* __restrict__ bcnt,
    float* __restrict__ ae) {
    __shared__ int anl[DPB];
    int b = blockIdx.x;
    int t = threadIdx.x;
    if (t < DPB) anl[t] = 0;
    __syncthreads();
    int e0 = b * BSTR;
    int c = bcnt[b];
    int e1 = e0 + (c < BSTR ? c : BSTR);
    for (int k = e0 + t; k < e1; k += 256) {
        uint2 r = bins[k];
        atomicAdd(&anl[r.x >> 24], (int)r.y);
    }
    __syncthreads();
    if (t < DPB) {
        int n = b * DPB + t;
        if (n < Nn) ae[n] = expf((float)anl[t] * (1.f / AFIX));
    }
}

// ---------------------------------------------------------------------------
// R23 aggregation: R5's PROVEN structure restored (R6's bundled
// {persistent work-steal + quarter-wave} regressed k_agg 45->65 µs at
// identical traffic — issue/latency structure, not bytes; reverted whole).
// ONE block per bucket, 512 threads (8 waves), phase 1 once per bucket,
// records LDS-staged, byte-offset records, __launch_bounds__(512,4).
// Only delta vs R5: fixed-stride bucket addressing (e0 = b*BSTR,
// total = min(bcnt[b], BSTR) <= CAP by construction -> fallback deleted).
// Phase 2: 8 waves x 8 dlocs, SPLIT-WAVE pairs (lanes 0-31 record k, lanes
// 32-63 record k+1; each lane a dim PAIR via one uint 2xbf16 load).
// Register accumulation; flush via shfl_xor(32); fused denom/div/ELU.
#define AGG_BODY(NR)                                                         \
    {                                                                        \
        uint2 rr[NR];                                                        \
        unsigned ww[NR];                                                     \
        _Pragma("unroll") for (int j = 0; j < NR; ++j)                       \
            rr[j] = lp[2 * j];                                               \
        _Pragma("unroll") for (int j = 0; j < NR; ++j)                       \
            ww[j] = *(const unsigned*)(whbB + (rr[j].x + hl4));              \
        _Pragma("unroll") for (int j = 0; j < NR; ++j) {                     \
            float aa = __uint_as_float(rr[j].y);                             \
            acc.x += aa * __uint_as_float(ww[j] << 16);                      \
            acc.y += aa * __uint_as_float(ww[j] & 0xFFFF0000u);              \
            den += aa;                                                       \
        }                                                                    \
        lp += 2 * NR;                                                        \
    }

__global__ __launch_bounds__(512, 4) void k_agg(
    const uint2* __restrict__ bins, const int* __restrict__ bcnt,
    const float* __restrict__ ae, const unsigned short* __restrict__ Whb,
    float* __restrict__ out) {
    __shared__ uint2 lrec[CAP];      // 12.3 KB (whb_byte_off, ae_f32)
    __shared__ int cnt[DPB];
    __shared__ int sbase[DPB];
    int b = blockIdx.x;
    int t = threadIdx.x;
    int lane = t & 63;
    int wave = t >> 6;               // 0..7
    int half = lane >> 5;            // 0: even records, 1: odd records
    int hl = lane & 31;              // dim pair index: dims 2*hl, 2*hl+1
    unsigned hl4 = (unsigned)hl << 2;
    int e0 = b * BSTR;
    int c = bcnt[b];
    int total = c < BSTR ? c : BSTR;
    int e1 = e0 + total;
    const char* whbB = (const char*)Whb;

    if (t < DPB) cnt[t] = 0;
    __syncthreads();

    // ---- phase 1: stage + rank (once per bucket) ----
    unsigned su[CAP / 512];
    float sa[CAP / 512];
    int srk[CAP / 512];
#pragma unroll
    for (int i = 0; i < CAP / 512; ++i) {
        int k = e0 + i * 512 + t;
        srk[i] = -1;
        if (k < e1) {
            uint2 r = bins[k];
            srk[i] = atomicAdd(&cnt[r.x >> 24], 1);
            su[i] = r.x;
            sa[i] = ae[(r.x >> 7) & 0x1FFFF];
        }
    }
    __syncthreads();
    // single-wave inclusive shfl-scan of cnt -> sbase
    if (t < DPB) {
        int v = cnt[t];
#pragma unroll
        for (int d = 1; d < DPB; d <<= 1) {
            int u = __shfl_up(v, d, 64);
            if (t >= d) v += u;
        }
        sbase[t] = v;
    }
    __syncthreads();
    // scatter into dloc-sorted LDS order: (byte_off, ae bits)
#pragma unroll
    for (int i = 0; i < CAP / 512; ++i) {
        if (srk[i] >= 0) {
            int dloc = su[i] >> 24;
            int pos = sbase[dloc] - cnt[dloc] + srk[i];
            lrec[pos] = make_uint2(su[i] & 0x00FFFF80u,
                                   __float_as_uint(sa[i]));
        }
    }
    __syncthreads();

    // ---- phase 2: wave owns dlocs [wave*8, wave*8+8) ----
    for (int d = wave * 8; d < wave * 8 + 8; ++d) {
        int k1 = sbase[d];
        int k = k1 - cnt[d];
        const uint2* lp = lrec + k + half;
        float2 acc = make_float2(0.f, 0.f);
        float den = 0.f;
        for (; k + 15 < k1; k += 16) AGG_BODY(8);
        for (; k + 7 < k1; k += 8) AGG_BODY(4);
        for (; k + 1 < k1; k += 2) AGG_BODY(1);
        if (k < k1) {  // odd tail: half 1 contributes zero
            uint2 rA = lrec[k];
            unsigned wA = *(const unsigned*)(whbB + (rA.x + hl4));
            float aA = half ? 0.f : __uint_as_float(rA.y);
            acc.x += aA * __uint_as_float(wA << 16);
            acc.y += aA * __uint_as_float(wA & 0xFFFF0000u);
            den += aA;
        }
        // flush: combine halves, divide, ELU, write float2
        float ax = acc.x + __shfl_xor(acc.x, 32, 64);
        float ay = acc.y + __shfl_xor(acc.y, 32, 64);
        float dn = den + __shfl_xor(den, 32, 64);
        if (half == 0) {
            int n = b * DPB + d;
            if (n < Nn) {
                float inv = 1.f / (dn + 1e-9f);
                float vx = ax * inv;
                float vy = ay * inv;
                vx = vx > 0.f ? vx : expm1f(vx);
                vy = vy > 0.f ? vy : expm1f(vy);
                *(float2*)&out[(size_t)n * OUTD + hl * 2] =
                    make_float2(vx, vy);
            }
        }
    }
}

// ---------------------------------------------------------------------------
extern "C" void kernel_launch(void* const* d_in, const int* in_sizes, int n_in,
                              void* d_out, int out_size, void* d_ws,
                              size_t ws_size, hipStream_t stream) {
    const float* h = (const float*)d_in[0];
    const void* ei = d_in[1];
    const float* ew = (const float*)d_in[2];
    const float* W = (const float*)d_in[3];
    const float* a = (const float*)d_in[4];
    float* out = (float*)d_out;

    unsigned short* Whb = (unsigned short*)d_ws;      // 6.4M u16 = 12.8 MB
    float* s1 = (float*)(Whb + (size_t)Nn * OUTD);    // 100,000 f
    float* s2 = s1 + Nn;                              // 100,000 f
    float* ae = s2 + Nn;                              // 100,000 f
    int* bcursor = (int*)(ae + Nn);                   // 2048 i [zeroed]
    uint2* bins = (uint2*)(bcursor + 2048);           // NB*BSTR x 8B = 19.2MB

    hipMemsetAsync(bcursor, 0, 2048 * sizeof(int), stream);

    k_fused<<<GB, 256, 0, stream>>>(h, W, a, Whb, s1, s2);
    k_binscatter<<<EB_BLOCKS, 512, 0, stream>>>(ei, ew, s1, s2, bcursor, bins);
    k_balpha<<<NB, 256, 0, stream>>>(bins, bcursor, ae);
    k_agg<<<NB, 512, 0, stream>>>(bins, bcursor, ae, Whb, out);
}